// Round 1
// baseline (1405.862 us; speedup 1.0000x reference)
//
#include <hip/hip_runtime.h>
#include <cstdint>
#include <cstddef>

// Problem constants (match reference)
#define BATCH  32
#define TSTEPS 1024
#define INDIM  512
#define HIDDIM 512
#define HTILE  64            // h columns per block
#define TC     32            // t-steps per chunk
#define NCHUNK (TSTEPS / TC) // 32
#define I4     (INDIM / 4)   // 128 float4 per row

// float(math.exp(-1.0/20.0))
constexpr float ALPHA = 0.951229424500714f;

// One block per (batch b, h-tile). 256 threads = 4 waves.
// Wave w computes z for t = t0 + w*8 + k (k=0..7), h = lane (0..63).
// W tile is staged transposed in LDS as float4 rows (conflict-free reads).
// Wave 0 owns the sequential membrane scan; z chunks are double-buffered in
// LDS so the scan of chunk c overlaps the GEMM of chunk c+1.
__global__ __launch_bounds__(256, 1)
void snn_fused(const float* __restrict__ x, const float* __restrict__ W,
               const float* __restrict__ bias, const float* __restrict__ thr,
               float* __restrict__ out)
{
    __shared__ float4 Wt4[I4][HTILE + 1];     // 128*65*16 = 133,120 B
    __shared__ float  zbuf[2][TC][HTILE];     // 16,384 B

    const int tid  = threadIdx.x;
    const int lane = tid & 63;
    const int wave = tid >> 6;
    const int b    = blockIdx.x >> 3;          // HIDDIM/HTILE == 8
    const int h0   = (blockIdx.x & 7) * HTILE;

    // ---- Stage W tile (rows h0..h0+63), transposed: Wt4[i4][h] = W[h0+h][4*i4..+3]
    {
        const float4* Wg = reinterpret_cast<const float4*>(W + (size_t)h0 * INDIM);
        for (int idx = tid; idx < HTILE * I4; idx += 256) {
            int r  = idx >> 7;    // h row 0..63
            int c4 = idx & 127;   // i4  0..127
            Wt4[c4][r] = Wg[r * I4 + c4];
        }
    }

    const float bb = bias[h0 + lane];
    const float tt = thr[h0 + lane];
    float mem = 0.0f;

    __syncthreads();

    const float4* xb = reinterpret_cast<const float4*>(x) + (size_t)b * TSTEPS * I4;

    for (int chunk = 0; chunk < NCHUNK; ++chunk) {
        const int t0 = chunk * TC;
        const int p  = chunk & 1;

        // ---- GEMM phase: 8 dot-products (t rows) per thread, h = lane
        {
            const float4* xrow = xb + (size_t)(t0 + wave * 8) * I4;
            float z[8];
#pragma unroll
            for (int k = 0; k < 8; ++k) z[k] = 0.0f;
#pragma unroll 4
            for (int i4 = 0; i4 < I4; ++i4) {
                float4 wv = Wt4[i4][lane];
#pragma unroll
                for (int k = 0; k < 8; ++k) {
                    float4 xv = xrow[k * I4 + i4];   // wave-uniform broadcast
                    z[k] = fmaf(xv.x, wv.x, z[k]);
                    z[k] = fmaf(xv.y, wv.y, z[k]);
                    z[k] = fmaf(xv.z, wv.z, z[k]);
                    z[k] = fmaf(xv.w, wv.w, z[k]);
                }
            }
#pragma unroll
            for (int k = 0; k < 8; ++k)
                zbuf[p][wave * 8 + k][lane] = z[k];
        }

        __syncthreads();

        // ---- Scan phase (wave 0 only), overlaps next chunk's GEMM
        if (wave == 0) {
            float* so = out + ((size_t)b * TSTEPS + t0) * HIDDIM + h0 + lane;
            for (int tc = 0; tc < TC; ++tc) {
                float z = zbuf[p][tc][lane] + bb;
                mem = fmaf(ALPHA, mem, z);
                bool s = (mem >= tt);
                so[(size_t)tc * HIDDIM] = s ? 1.0f : 0.0f;
                mem = s ? 0.0f : mem;
            }
        }
    }

    // ---- mem_final
    if (wave == 0) {
        out[(size_t)BATCH * TSTEPS * HIDDIM + (size_t)b * HIDDIM + h0 + lane] = mem;
    }
}

extern "C" void kernel_launch(void* const* d_in, const int* in_sizes, int n_in,
                              void* d_out, int out_size, void* d_ws, size_t ws_size,
                              hipStream_t stream)
{
    const float* x   = (const float*)d_in[0];
    const float* W   = (const float*)d_in[1];
    const float* bsv = (const float*)d_in[2];
    const float* thr = (const float*)d_in[3];
    float* out = (float*)d_out;

    (void)in_sizes; (void)n_in; (void)out_size; (void)d_ws; (void)ws_size;

    dim3 grid(BATCH * (HIDDIM / HTILE));  // 256 blocks
    dim3 block(256);
    hipLaunchKernelGGL(snn_fused, grid, block, 0, stream, x, W, bsv, thr, out);
}

// Round 2
// 389.911 us; speedup vs baseline: 3.6056x; 3.6056x over previous
//
#include <hip/hip_runtime.h>
#include <cstdint>
#include <cstddef>

// Problem constants
#define BATCH  32
#define TSTEPS 1024
#define INDIM  512
#define HIDDIM 512
#define MTOT   (BATCH * TSTEPS)   // 32768 GEMM rows

// GEMM tiling
#define MB 128
#define NB 128
#define KC 32
#define KTILES (INDIM / KC)       // 16
#define NBLK   (HIDDIM / NB)      // 4

constexpr float ALPHA = 0.951229424500714f;  // exp(-1/20)

// ---------------------------------------------------------------------------
// Kernel 1: z[m][n] = sum_k x[m][k] * W[n][k]   (raw, bias added in scan)
// 256 threads, 128x128 tile, 8x8 accum/thread, Kc=32 LDS single-buffer with
// next-tile global loads issued before the compute phase (latency hidden).
// Accumulation is a single fmaf chain in ascending k  -> bit-identical to the
// round-1 kernel that validated with absmax 0.0.
// ---------------------------------------------------------------------------
__global__ __launch_bounds__(256)
void snn_gemm(const float* __restrict__ x, const float* __restrict__ W,
              float* __restrict__ z)
{
    __shared__ float Asm[KC][MB];   // 16 KB, [k][m] : conflict-free b128 reads
    __shared__ float Bsm[KC][NB];   // 16 KB, [k][n]

    const int tid = threadIdx.x;
    const int mb  = blockIdx.x / NBLK;
    const int nb  = blockIdx.x % NBLK;
    const int m0  = mb * MB;
    const int n0  = nb * NB;

    // staging map: thread -> (row, 4 consecutive float4 along k)
    const int sr = tid >> 1;           // 0..127
    const int sc = (tid & 1) * 4;      // float4 index 0 or 4

    const float4* Ag = reinterpret_cast<const float4*>(x + (size_t)(m0 + sr) * INDIM) + sc;
    const float4* Bg = reinterpret_cast<const float4*>(W + (size_t)(n0 + sr) * INDIM) + sc;

    // compute map: thread -> 8x8 sub-tile
    const int cm = (tid >> 4) * 8;     // 0..120
    const int cn = (tid & 15) * 8;     // 0..120

    float acc[8][8];
#pragma unroll
    for (int i = 0; i < 8; ++i)
#pragma unroll
        for (int j = 0; j < 8; ++j) acc[i][j] = 0.0f;

    float4 sa[4], sb[4];
#pragma unroll
    for (int j = 0; j < 4; ++j) { sa[j] = Ag[j]; sb[j] = Bg[j]; }

    for (int kt = 0; kt < KTILES; ++kt) {
        __syncthreads();   // previous compute done reading LDS
#pragma unroll
        for (int j = 0; j < 4; ++j) {
            const int kq = (sc + j) * 4;
            Asm[kq + 0][sr] = sa[j].x;
            Asm[kq + 1][sr] = sa[j].y;
            Asm[kq + 2][sr] = sa[j].z;
            Asm[kq + 3][sr] = sa[j].w;
            Bsm[kq + 0][sr] = sb[j].x;
            Bsm[kq + 1][sr] = sb[j].y;
            Bsm[kq + 2][sr] = sb[j].z;
            Bsm[kq + 3][sr] = sb[j].w;
        }
        __syncthreads();

        // issue next tile's global loads now; they complete during compute
        if (kt + 1 < KTILES) {
            Ag += KC / 4;
            Bg += KC / 4;
#pragma unroll
            for (int j = 0; j < 4; ++j) { sa[j] = Ag[j]; sb[j] = Bg[j]; }
        }

        // compute 32 k-steps from LDS
#pragma unroll 8
        for (int kc = 0; kc < KC; ++kc) {
            float4 a0 = *reinterpret_cast<const float4*>(&Asm[kc][cm]);
            float4 a1 = *reinterpret_cast<const float4*>(&Asm[kc][cm + 4]);
            float4 b0 = *reinterpret_cast<const float4*>(&Bsm[kc][cn]);
            float4 b1 = *reinterpret_cast<const float4*>(&Bsm[kc][cn + 4]);
            const float av[8] = {a0.x, a0.y, a0.z, a0.w, a1.x, a1.y, a1.z, a1.w};
            const float bv[8] = {b0.x, b0.y, b0.z, b0.w, b1.x, b1.y, b1.z, b1.w};
#pragma unroll
            for (int i = 0; i < 8; ++i)
#pragma unroll
                for (int j = 0; j < 8; ++j)
                    acc[i][j] = fmaf(av[i], bv[j], acc[i][j]);
        }
    }

    // epilogue: store raw z
#pragma unroll
    for (int i = 0; i < 8; ++i) {
        float* zr = z + (size_t)(m0 + cm + i) * HIDDIM + n0 + cn;
        float4 v0 = {acc[i][0], acc[i][1], acc[i][2], acc[i][3]};
        float4 v1 = {acc[i][4], acc[i][5], acc[i][6], acc[i][7]};
        *reinterpret_cast<float4*>(zr)     = v0;
        *reinterpret_cast<float4*>(zr + 4) = v1;
    }
}

// ---------------------------------------------------------------------------
// Kernel 2: sequential membrane scan per (b,h) chain. 16384 chains.
// z lives in d_ws (restrict, prefetch-friendly) or in-place in d_out.
// ---------------------------------------------------------------------------
template <bool INPLACE>
__global__ __launch_bounds__(64)
void snn_scan(const float* zsrc, float* out,
              const float* __restrict__ bias, const float* __restrict__ thr)
{
    const int h = (blockIdx.x & 7) * 64 + threadIdx.x;  // 0..511
    const int b = blockIdx.x >> 3;                      // 0..31

    const float bb = bias[h];
    const float tt = thr[h];
    float mem = 0.0f;

    const size_t base = ((size_t)b * TSTEPS) * HIDDIM + h;
    const float* zp = zsrc + base;
    float* sp = out + base;

    for (int t = 0; t < TSTEPS; t += 8) {
        float zl[8];
#pragma unroll
        for (int j = 0; j < 8; ++j)
            zl[j] = zp[(size_t)(t + j) * HIDDIM];
#pragma unroll
        for (int j = 0; j < 8; ++j) {
            float zv = zl[j] + bb;
            mem = fmaf(ALPHA, mem, zv);
            bool s = (mem >= tt);
            sp[(size_t)(t + j) * HIDDIM] = s ? 1.0f : 0.0f;
            mem = s ? 0.0f : mem;
        }
    }
    out[(size_t)MTOT * HIDDIM + (size_t)b * HIDDIM + h] = mem;
}

extern "C" void kernel_launch(void* const* d_in, const int* in_sizes, int n_in,
                              void* d_out, int out_size, void* d_ws, size_t ws_size,
                              hipStream_t stream)
{
    const float* x    = (const float*)d_in[0];
    const float* W    = (const float*)d_in[1];
    const float* bias = (const float*)d_in[2];
    const float* thr  = (const float*)d_in[3];
    float* out = (float*)d_out;

    (void)in_sizes; (void)n_in; (void)out_size;

    const size_t z_bytes = (size_t)MTOT * HIDDIM * sizeof(float);  // 64 MB
    float* zbuf;
    bool use_ws = (ws_size >= z_bytes);
    zbuf = use_ws ? (float*)d_ws : out;   // fallback: in-place in spike region

    dim3 ggrid((MTOT / MB) * NBLK);  // 1024 blocks
    hipLaunchKernelGGL(snn_gemm, ggrid, dim3(256), 0, stream, x, W, zbuf);

    dim3 sgrid(BATCH * (HIDDIM / 64));   // 256 blocks x 64 threads
    if (use_ws)
        hipLaunchKernelGGL((snn_scan<false>), sgrid, dim3(64), 0, stream, zbuf, out, bias, thr);
    else
        hipLaunchKernelGGL((snn_scan<true>),  sgrid, dim3(64), 0, stream, zbuf, out, bias, thr);
}

// Round 3
// 326.720 us; speedup vs baseline: 4.3030x; 1.1934x over previous
//
#include <hip/hip_runtime.h>
#include <cstdint>
#include <cstddef>

// Problem constants
#define BATCH  32
#define TSTEPS 1024
#define INDIM  512
#define HIDDIM 512
#define MTOT   (BATCH * TSTEPS)   // 32768 GEMM rows

// GEMM tiling
#define MB 128
#define NB 128
#define KC 32
#define KTILES (INDIM / KC)       // 16
#define NBLK   (HIDDIM / NB)      // 4

constexpr float ALPHA = 0.951229424500714f;  // exp(-1/20)

// 16B-group permutation: spreads the 16 per-wave B-read addresses over all
// 8 bank quads (was 4-way conflict on quads {0,2,4,6}). Placement-only.
__device__ __forceinline__ int swzg(int g) { return g ^ (g >> 3); }

// ---------------------------------------------------------------------------
// Kernel 1: z[m][n] = sum_k x[m][k] * W[n][k]  (raw; bias added in scan)
// 256 threads, 128x128 tile, 8x8 accum/thread, KC=32 LDS with reg-staged
// next-tile loads. Ascending-k single fmaf chain -> bit-identical to the
// validated round-1/2 kernels.
// ---------------------------------------------------------------------------
__global__ __launch_bounds__(256)
void snn_gemm(const float* __restrict__ x, const float* __restrict__ W,
              float* __restrict__ z)
{
    __shared__ float Asm[KC][MB];   // 16 KB, [k][m], column-swizzled
    __shared__ float Bsm[KC][NB];   // 16 KB, [k][n], column-swizzled

    const int tid = threadIdx.x;
    const int mb  = blockIdx.x / NBLK;
    const int nb  = blockIdx.x % NBLK;
    const int m0  = mb * MB;
    const int n0  = nb * NB;

    // staging map: thread -> (row, 4 consecutive float4 along k)
    const int sr = tid >> 1;           // 0..127 (column in LDS tile)
    const int sc = (tid & 1) * 4;      // float4 index 0 or 4
    // swizzled float position of column sr within each LDS row
    const int srg = sr >> 2;
    const int swr = (swzg(srg) << 2) | (sr & 3);

    const float4* Ag = reinterpret_cast<const float4*>(x + (size_t)(m0 + sr) * INDIM) + sc;
    const float4* Bg = reinterpret_cast<const float4*>(W + (size_t)(n0 + sr) * INDIM) + sc;

    // compute map: thread -> 8x8 sub-tile; swizzled float4 read offsets
    const int cm = (tid >> 4) * 8;     // 0..120
    const int cn = (tid & 15) * 8;     // 0..120
    const int am0 = swzg(cm >> 2);
    const int am1 = swzg((cm >> 2) + 1);
    const int bn0 = swzg(cn >> 2);
    const int bn1 = swzg((cn >> 2) + 1);

    float acc[8][8];
#pragma unroll
    for (int i = 0; i < 8; ++i)
#pragma unroll
        for (int j = 0; j < 8; ++j) acc[i][j] = 0.0f;

    float4 sa[4], sb[4];
#pragma unroll
    for (int j = 0; j < 4; ++j) { sa[j] = Ag[j]; sb[j] = Bg[j]; }

    for (int kt = 0; kt < KTILES; ++kt) {
        __syncthreads();   // previous compute done reading LDS
#pragma unroll
        for (int j = 0; j < 4; ++j) {
            const int kq = (sc + j) * 4;
            Asm[kq + 0][swr] = sa[j].x;
            Asm[kq + 1][swr] = sa[j].y;
            Asm[kq + 2][swr] = sa[j].z;
            Asm[kq + 3][swr] = sa[j].w;
            Bsm[kq + 0][swr] = sb[j].x;
            Bsm[kq + 1][swr] = sb[j].y;
            Bsm[kq + 2][swr] = sb[j].z;
            Bsm[kq + 3][swr] = sb[j].w;
        }
        __syncthreads();

        // issue next tile's global loads now; they complete during compute
        if (kt + 1 < KTILES) {
            Ag += KC / 4;
            Bg += KC / 4;
#pragma unroll
            for (int j = 0; j < 4; ++j) { sa[j] = Ag[j]; sb[j] = Bg[j]; }
        }

        // compute 32 k-steps from LDS
#pragma unroll 8
        for (int kc = 0; kc < KC; ++kc) {
            const float4* Ar = reinterpret_cast<const float4*>(&Asm[kc][0]);
            const float4* Br = reinterpret_cast<const float4*>(&Bsm[kc][0]);
            float4 a0 = Ar[am0];
            float4 a1 = Ar[am1];
            float4 b0 = Br[bn0];
            float4 b1 = Br[bn1];
            const float av[8] = {a0.x, a0.y, a0.z, a0.w, a1.x, a1.y, a1.z, a1.w};
            const float bv[8] = {b0.x, b0.y, b0.z, b0.w, b1.x, b1.y, b1.z, b1.w};
#pragma unroll
            for (int i = 0; i < 8; ++i)
#pragma unroll
                for (int j = 0; j < 8; ++j)
                    acc[i][j] = fmaf(av[i], bv[j], acc[i][j]);
        }
    }

    // epilogue: store raw z
#pragma unroll
    for (int i = 0; i < 8; ++i) {
        float* zr = z + (size_t)(m0 + cm + i) * HIDDIM + n0 + cn;
        float4 v0 = {acc[i][0], acc[i][1], acc[i][2], acc[i][3]};
        float4 v1 = {acc[i][4], acc[i][5], acc[i][6], acc[i][7]};
        *reinterpret_cast<float4*>(zr)     = v0;
        *reinterpret_cast<float4*>(zr + 4) = v1;
    }
}

// ---------------------------------------------------------------------------
// Kernel 2: sequential membrane scan per (b,h) chain. 16384 chains = 256
// waves = 1 wave/CU -> pure latency problem. Register ring of D=8 groups
// (8 t-steps each) keeps ~64 loads in flight. Slot index is compile-time
// (loop unrolled by D) so pf[] stays in registers.
// In-place safe: load of group g is issued D iterations before store to g.
// ---------------------------------------------------------------------------
#define SCAND 8

__global__ __launch_bounds__(64)
void snn_scan(const float* zsrc, float* out,
              const float* __restrict__ bias, const float* __restrict__ thr)
{
    const int h = (blockIdx.x & 7) * 64 + threadIdx.x;  // 0..511
    const int b = blockIdx.x >> 3;                      // 0..31

    const float bb = bias[h];
    const float tt = thr[h];
    float mem = 0.0f;

    const size_t base = ((size_t)b * TSTEPS) * HIDDIM + h;
    const float* zp = zsrc + base;
    float* sp = out + base;

    float pf[SCAND][8];

    // prologue: fill the ring
#pragma unroll
    for (int g = 0; g < SCAND; ++g)
#pragma unroll
        for (int j = 0; j < 8; ++j)
            pf[g][j] = zp[(size_t)(g * 8 + j) * HIDDIM];

    // main: 120 groups with prefetch (120 % 8 == 0 -> slot compile-time)
#pragma unroll 8
    for (int t8 = 0; t8 < 120; ++t8) {
        const int slot = t8 & (SCAND - 1);
        float cur[8];
#pragma unroll
        for (int j = 0; j < 8; ++j) cur[j] = pf[slot][j];
        // prefetch group t8+8
#pragma unroll
        for (int j = 0; j < 8; ++j)
            pf[slot][j] = zp[(size_t)((t8 + SCAND) * 8 + j) * HIDDIM];
        // compute + store 8 steps
#pragma unroll
        for (int j = 0; j < 8; ++j) {
            float zv = cur[j] + bb;
            mem = fmaf(ALPHA, mem, zv);
            bool s = (mem >= tt);
            sp[(size_t)(t8 * 8 + j) * HIDDIM] = s ? 1.0f : 0.0f;
            mem = s ? 0.0f : mem;
        }
    }

    // epilogue: last 8 groups, no prefetch
#pragma unroll
    for (int t8 = 120; t8 < 128; ++t8) {
        const int slot = t8 & (SCAND - 1);
#pragma unroll
        for (int j = 0; j < 8; ++j) {
            float zv = pf[slot][j] + bb;
            mem = fmaf(ALPHA, mem, zv);
            bool s = (mem >= tt);
            sp[(size_t)(t8 * 8 + j) * HIDDIM] = s ? 1.0f : 0.0f;
            mem = s ? 0.0f : mem;
        }
    }

    out[(size_t)MTOT * HIDDIM + (size_t)b * HIDDIM + h] = mem;
}

extern "C" void kernel_launch(void* const* d_in, const int* in_sizes, int n_in,
                              void* d_out, int out_size, void* d_ws, size_t ws_size,
                              hipStream_t stream)
{
    const float* x    = (const float*)d_in[0];
    const float* W    = (const float*)d_in[1];
    const float* bias = (const float*)d_in[2];
    const float* thr  = (const float*)d_in[3];
    float* out = (float*)d_out;

    (void)in_sizes; (void)n_in; (void)out_size;

    const size_t z_bytes = (size_t)MTOT * HIDDIM * sizeof(float);  // 64 MB
    const bool use_ws = (ws_size >= z_bytes);
    float* zbuf = use_ws ? (float*)d_ws : out;   // fallback: in-place

    dim3 ggrid((MTOT / MB) * NBLK);  // 1024 blocks
    hipLaunchKernelGGL(snn_gemm, ggrid, dim3(256), 0, stream, x, W, zbuf);

    dim3 sgrid(BATCH * (HIDDIM / 64));   // 256 blocks x 64 threads
    hipLaunchKernelGGL(snn_scan, sgrid, dim3(64), 0, stream, zbuf, out, bias, thr);
}